// Round 8
// baseline (16758.957 us; speedup 1.0000x reference)
//
#include <hip/hip_runtime.h>

#define T_STEPS 256
#define BATCH   512
#define RB      4      // batch rows per block
#define NBLK    128    // NBLK * RB == BATCH

__device__ __forceinline__ float sigm(float x){ return 1.f / (1.f + expf(-x)); }

// Exact-f32 implementation, all buffers float32 (verified R6/R7 telemetry).
// Block b owns batch rows [b*RB, b*RB+RB) for all T steps. 1024 threads.
__global__ __launch_bounds__(1024) void marn_f32(
  const float* __restrict__ eeg, const float* __restrict__ eog,
  const float* __restrict__ Ww,  const float* __restrict__ Wb,
  const float* __restrict__ Uw,  const float* __restrict__ Ub,
  const float* __restrict__ Vw,  const float* __restrict__ Vb,
  const float* __restrict__ A1,  const float* __restrict__ a1,
  const float* __restrict__ A2,  const float* __restrict__ a2,
  const float* __restrict__ D10, const float* __restrict__ e10,
  const float* __restrict__ D20, const float* __restrict__ e20,
  const float* __restrict__ D11, const float* __restrict__ e11,
  const float* __restrict__ D21, const float* __restrict__ e21,
  float* __restrict__ out)
{
  __shared__ float xS[2][RB*128];     // staged inputs         [mod][r*128+c]
  __shared__ float hS[2][RB*128];     // h state
  __shared__ float zS[2][RB*128];     // z state
  __shared__ float cS[2][RB*128];     // c state
  __shared__ float gS[2][RB*512];     // gate sums             [mod][r*512+n]
  __shared__ float yS[RB*128];        // A1-MLP hidden
  __shared__ float lgS[RB*1024];      // logits                [r*1024+n]
  __shared__ float attS[2][RB*512];   // att = softmax * h     [mod][r*512+j]
  __shared__ float uS[2][RB*128];     // D1-MLP hidden

  const int tid = threadIdx.x;
  const int r0  = blockIdx.x * RB;

  // zero c (h,z unread at t=0; guarded by t>0)
  for (int i = tid; i < 2*RB*128; i += 1024) ((float*)cS)[i] = 0.f;
  __syncthreads();

  // per-stage thread maps
  const int modg = tid >> 9, ng = tid & 511;                     // S1 gemm
  const int mode = tid >> 9, re = (tid>>7)&3, cce = tid & 127;   // S1 epilogue
  const int r2a = tid >> 7, n2a = tid & 127;                     // S2a (tid<512)
  const int rs  = tid >> 8, fs = tid & 255;                      // softmax
  const int m23 = tid >> 9, r3 = (tid>>7)&3, n3 = tid & 127;     // S3a/S3b

  for (int t = 0; t < T_STEPS; ++t){
    // ---- S0: stage x for both modalities (1024 = 2*4*128 exactly) ----
    {
      int m2 = tid >> 9, rem = tid & 511;
      int r = rem >> 7, c = rem & 127;
      const float* src = m2 ? eog : eeg;
      xS[m2][rem] = src[((size_t)t*BATCH + r0 + r)*128 + c];
    }
    __syncthreads();                                   // A

    // ---- S1 gemm: gates[mod][r][n] = x@Ww (+ h@Uw + z@Vw if t>0) ----
    {
      float a0=0.f, a1_=0.f, a2_=0.f, a3=0.f;
      const float* wp = Ww + ng;
      const float* xp = xS[modg];
      for (int k = 0; k < 128; ++k){
        float w = wp[(size_t)k*512];
        a0 += xp[k]*w; a1_ += xp[128+k]*w; a2_ += xp[256+k]*w; a3 += xp[384+k]*w;
      }
      if (t > 0){
        const float* up = Uw + ng; const float* hp = hS[modg];
        for (int k = 0; k < 128; ++k){
          float w = up[(size_t)k*512];
          a0 += hp[k]*w; a1_ += hp[128+k]*w; a2_ += hp[256+k]*w; a3 += hp[384+k]*w;
        }
        const float* vp = Vw + ng; const float* zp = zS[modg];
        for (int k = 0; k < 128; ++k){
          float w = vp[(size_t)k*512];
          a0 += zp[k]*w; a1_ += zp[128+k]*w; a2_ += zp[256+k]*w; a3 += zp[384+k]*w;
        }
      }
      gS[modg][0*512+ng]=a0; gS[modg][1*512+ng]=a1_;
      gS[modg][2*512+ng]=a2_; gS[modg][3*512+ng]=a3;
    }
    __syncthreads();                                   // B

    // ---- S1 epilogue: LSTHM cell update ----
    {
      float bF = Wb[cce],     bI = Wb[128+cce],
            bO = Wb[256+cce], bC = Wb[384+cce];
      if (t > 0){
        bF += Ub[cce]     + Vb[cce];
        bI += Ub[128+cce] + Vb[128+cce];
        bO += Ub[256+cce] + Vb[256+cce];
        bC += Ub[384+cce] + Vb[384+cce];
      }
      const float* gp = gS[mode] + re*512;
      float f  = sigm(gp[cce]       + bF);
      float ii = sigm(gp[128 + cce] + bI);
      float o  = sigm(gp[256 + cce] + bO);
      float ch = tanhf(gp[384 + cce] + bC);
      int ix = re*128 + cce;
      float cn = f*cS[mode][ix] + ii*ch;
      cS[mode][ix] = cn;
      hS[mode][ix] = tanhf(cn)*o;
    }
    __syncthreads();                                   // C

    // ---- S2a: y = tanh([h0|h1] @ A1 + a1) ----
    if (tid < 512){
      float acc = 0.f;
      const float* ap = A1 + n2a;
      const float* h0p = hS[0] + r2a*128;
      const float* h1p = hS[1] + r2a*128;
      for (int k = 0; k < 128; ++k) acc += h0p[k]*ap[(size_t)k*128];
      for (int k = 0; k < 128; ++k) acc += h1p[k]*ap[(size_t)(128+k)*128];
      yS[r2a*128 + n2a] = tanhf(acc + a1[n2a]);
    }
    __syncthreads();                                   // D

    // ---- S2b: logits = y @ A2 + a2  (n = tid, 4 rows) ----
    {
      float b0=0.f, b1=0.f, b2=0.f, b3=0.f;
      const float* ap = A2 + tid;
      for (int k = 0; k < 128; ++k){
        float w = ap[(size_t)k*1024];
        b0 += yS[k]*w; b1 += yS[128+k]*w; b2 += yS[256+k]*w; b3 += yS[384+k]*w;
      }
      float ab_ = a2[tid];
      lgS[0*1024+tid]=b0+ab_; lgS[1*1024+tid]=b1+ab_;
      lgS[2*1024+tid]=b2+ab_; lgS[3*1024+tid]=b3+ab_;
    }
    __syncthreads();                                   // E

    // ---- softmax over the 4 attentions (stride 256) * tiled-h ----
    {
      const float* lp = lgS + rs*1024;
      float v0 = lp[fs], v1 = lp[256+fs], v2 = lp[512+fs], v3 = lp[768+fs];
      float m = fmaxf(fmaxf(v0,v1), fmaxf(v2,v3));
      float e0=expf(v0-m), e1=expf(v1-m), e2=expf(v2-m), e3=expf(v3-m);
      float inv = 1.f/(e0+e1+e2+e3);
      float h0v = hS[0][rs*128 + (fs&127)];
      float h1v = hS[1][rs*128 + (fs&127)];
      attS[0][rs*512 + fs]       = e0*inv*h0v;
      attS[0][rs*512 + 256 + fs] = e1*inv*h0v;
      attS[1][rs*512 + fs]       = e2*inv*h1v;
      attS[1][rs*512 + 256 + fs] = e3*inv*h1v;
    }
    __syncthreads();                                   // F

    // ---- S3a: u = tanh(att @ D1 + e1) ----
    {
      float acc = 0.f;
      const float* dp = (m23 ? D11 : D10) + n3;
      const float* atp = attS[m23] + r3*512;
      for (int k = 0; k < 512; ++k) acc += atp[k]*dp[(size_t)k*128];
      uS[m23][r3*128+n3] = tanhf(acc + (m23 ? e11 : e10)[n3]);
    }
    __syncthreads();                                   // G

    // ---- S3b: z = u @ D2 + e2 ; write state + output ----
    {
      float acc = 0.f;
      const float* dp = (m23 ? D21 : D20) + n3;
      const float* up = uS[m23] + r3*128;
      for (int k = 0; k < 128; ++k) acc += up[k]*dp[(size_t)k*128];
      float z = acc + (m23 ? e21 : e20)[n3];
      zS[m23][r3*128+n3] = z;
      out[((size_t)t*BATCH + r0 + r3)*256 + m23*128 + n3] = z;
    }
    __syncthreads();                                   // H
  }
}

extern "C" void kernel_launch(void* const* d_in, const int* in_sizes, int n_in,
                              void* d_out, int out_size, void* d_ws, size_t ws_size,
                              hipStream_t stream)
{
  const float* eeg = (const float*)d_in[0];
  const float* eog = (const float*)d_in[1];
  const float* Ww  = (const float*)d_in[2];
  const float* Wb  = (const float*)d_in[3];
  const float* Uw  = (const float*)d_in[4];
  const float* Ub  = (const float*)d_in[5];
  const float* Vw  = (const float*)d_in[6];
  const float* Vb  = (const float*)d_in[7];
  const float* A1  = (const float*)d_in[8];
  const float* a1  = (const float*)d_in[9];
  const float* A2  = (const float*)d_in[10];
  const float* a2  = (const float*)d_in[11];
  const float* D10 = (const float*)d_in[12];
  const float* e10 = (const float*)d_in[13];
  const float* D20 = (const float*)d_in[14];
  const float* e20 = (const float*)d_in[15];
  const float* D11 = (const float*)d_in[16];
  const float* e11 = (const float*)d_in[17];
  const float* D21 = (const float*)d_in[18];
  const float* e21 = (const float*)d_in[19];

  marn_f32<<<NBLK, 1024, 0, stream>>>(eeg, eog, Ww, Wb, Uw, Ub, Vw, Vb,
                                      A1, a1, A2, a2, D10, e10, D20, e20,
                                      D11, e11, D21, e21, (float*)d_out);
}

// Round 9
// 10052.886 us; speedup vs baseline: 1.6671x; 1.6671x over previous
//
#include <hip/hip_runtime.h>

typedef unsigned short u16;
typedef unsigned int   u32;
typedef __attribute__((ext_vector_type(8))) __bf16 bf16x8;
typedef __attribute__((ext_vector_type(4))) float  f32x4;

#define T_STEPS 256
#define BATCH   512
#define RB      4
#define NBLK    128

__device__ __forceinline__ u16 f2b(float f){
  u32 x = __float_as_uint(f);
  return (u16)((x + 0x7fffu + ((x >> 16) & 1u)) >> 16);
}
__device__ __forceinline__ float sigm_f(float x){ return 1.f/(1.f + __expf(-x)); }
__device__ __forceinline__ float tanh_f(float x){
  x = fminf(15.f, fmaxf(-15.f, x));
  float e = __expf(2.f*x);
  return (e - 1.f)/(e + 1.f);
}
__device__ __forceinline__ f32x4 MF(bf16x8 a, bf16x8 b, f32x4 c){
  return __builtin_amdgcn_mfma_f32_16x16x32_bf16(a, b, c, 0, 0, 0);
}

// MFMA 16x16x32 bf16 lane maps (HW-verified m89):
//   A: row=lane&15, k=(lane>>4)*8+j ; B: col=lane&15, same k ; D: col=lane&15, row=(lane>>4)*4+reg
// LDS A-tile: row stride RS bytes, XOR swizzle byte^=(r&7)<<4 (bank-conflict-free, <=2-way)
__device__ __forceinline__ bf16x8 frA(const u16* buf, int l, int kc, int RS){
  int r = l & 15;
  int byte = r*RS + kc*64 + ((l >> 4) << 4);
  byte ^= (r & 7) << 4;
  return *(const bf16x8*)((const char*)buf + byte);
}
__device__ __forceinline__ void st16(u16* buf, int r, int c, u16 v, int RS){
  int byte = r*RS + c*2; byte ^= (r & 7) << 4;
  *(u16*)((char*)buf + byte) = v;
}
// fragment-packed global weights: [nt][kt][lane][8] bf16, one 16B load/lane
__device__ __forceinline__ bf16x8 frB(const u16* pk, int nt, int kt, int KT, int l){
  return *(const bf16x8*)(pk + ((((nt*KT + kt) << 6) + l) << 3));
}

// f32 src -> bf16 fragment-packed dst
__global__ void pack_w(const float* __restrict__ src, u16* __restrict__ dst,
                       int Ksrc, int N, int ktOff, int KT)
{
  int i = blockIdx.x*256 + threadIdx.x;
  if (i >= Ksrc*N) return;
  int j = i & 7, l = (i >> 3) & 63, p = i >> 9;
  int nkt = Ksrc >> 5;
  int kt = p % nkt, nt = p / nkt;
  int k = (kt << 5) + ((l >> 4) << 3) + j;
  int n = (nt << 4) + (l & 15);
  dst[(((nt*KT + ktOff + kt) << 6) + l)*8 + j] = f2b(src[(size_t)k*N + n]);
}

// f32 bias table: [0,512) Wb ; [512,1024) Wb+Ub+Vb ; [1024,1152) a1 ;
// [1152,2176) a2 ; [2176) e10 ; [2304) e20 ; [2432) e11 ; [2560) e21
__global__ void pack_bias(const float* Wb, const float* Ub, const float* Vb,
                          const float* a1, const float* a2,
                          const float* e10, const float* e20,
                          const float* e11, const float* e21, float* bout)
{
  int i = blockIdx.x*256 + threadIdx.x;
  if (i >= 2688) return;
  float v;
  if      (i < 512)  v = Wb[i];
  else if (i < 1024) { int n = i - 512; v = Wb[n] + Ub[n] + Vb[n]; }
  else if (i < 1152) v = a1[i - 1024];
  else if (i < 2176) v = a2[i - 1152];
  else if (i < 2304) v = e10[i - 2176];
  else if (i < 2432) v = e20[i - 2304];
  else if (i < 2560) v = e11[i - 2432];
  else               v = e21[i - 2560];
  bout[i] = v;
}

// 128 blocks x 1024 threads (16 waves); block owns batch rows [b*4, b*4+4).
// One M=16 tile carries both modalities: rows 0-3 = mod0, rows 8-11 = mod1.
__global__ __launch_bounds__(1024) void marn_mfma(
  const float* __restrict__ eeg, const float* __restrict__ eog,
  const u16* __restrict__ UVWt, const u16* __restrict__ A1t,
  const u16* __restrict__ A2t,  const u16* __restrict__ D10t,
  const u16* __restrict__ D20t, const u16* __restrict__ D11t,
  const u16* __restrict__ D21t, const float* __restrict__ bias,
  float* __restrict__ out)
{
  __shared__ u16  aS1[16*384];    // [x|h|z] bf16, RS=768
  __shared__ u16  aS2a[16*256];   // [h0|h1], RS=512
  __shared__ u16  aS2b[16*128];   // y, RS=256
  __shared__ u16  aS3a[16*512];   // att, RS=1024
  __shared__ u16  aS3b[16*128];   // u, RS=256
  __shared__ float gS[2][4][512];
  __shared__ float lgS[4][1024];
  __shared__ float cS[2][4][128];
  __shared__ float hS[2][4][128];
  __shared__ float bsh[2688];

  const int tid = threadIdx.x;
  const int w = tid >> 6, l = tid & 63;
  const int hi = l >> 4, li = l & 15;
  const int r0 = blockIdx.x * RB;

  for (int i = tid; i < 2688;   i += 1024) bsh[i] = bias[i];
  for (int i = tid; i < 16*384; i += 1024) aS1[i] = 0;
  for (int i = tid; i < 16*256; i += 1024) aS2a[i] = 0;
  for (int i = tid; i < 16*128; i += 1024) aS2b[i] = 0;
  for (int i = tid; i < 16*512; i += 1024) aS3a[i] = 0;
  for (int i = tid; i < 16*128; i += 1024) aS3b[i] = 0;
  ((float*)cS)[tid] = 0.f;                  // 2*4*128 == 1024
  __syncthreads();

  for (int t = 0; t < T_STEPS; ++t){
    // ---- S0: stage x (bf16) ----
    {
      int m = tid >> 9, r = (tid >> 7) & 3, c = tid & 127;
      float xv = (m ? eog : eeg)[((size_t)t*BATCH + r0 + r)*128 + c];
      st16(aS1, m*8 + r, c, f2b(xv), 768);
    }
    __syncthreads();                               // A

    // ---- S1: gates = [x|h|z] @ [Ww;Uw;Vw]  (wave w: nt = 2w,2w+1) ----
    {
      bf16x8 af[12];
      #pragma unroll
      for (int kc = 0; kc < 12; ++kc) af[kc] = frA(aS1, l, kc, 768);
      #pragma unroll
      for (int q = 0; q < 2; ++q){
        int nt = w*2 + q;
        f32x4 acc = {0,0,0,0};
        #pragma unroll
        for (int kc = 0; kc < 12; ++kc)
          acc = MF(af[kc], frB(UVWt, nt, kc, 12, l), acc);
        if (hi == 0 || hi == 2){
          int mod = hi >> 1;
          #pragma unroll
          for (int jr = 0; jr < 4; ++jr)
            gS[mod][jr][nt*16 + li] = acc[jr];
        }
      }
    }
    __syncthreads();                               // B

    // ---- S1ep: LSTHM cell update (2 mods x 4 rows x 128 cols) ----
    {
      int mod = tid >> 9, r = (tid >> 7) & 3, n = tid & 127;
      const float* bg = bsh + (t == 0 ? 0 : 512);
      float f  = sigm_f(gS[mod][r][n]     + bg[n]);
      float ii = sigm_f(gS[mod][r][128+n] + bg[128+n]);
      float o  = sigm_f(gS[mod][r][256+n] + bg[256+n]);
      float ch = tanh_f(gS[mod][r][384+n] + bg[384+n]);
      float cn = f*cS[mod][r][n] + ii*ch;
      cS[mod][r][n] = cn;
      float hn = tanh_f(cn)*o;
      hS[mod][r][n] = hn;
      u16 hb = f2b(hn);
      st16(aS1,  mod*8 + r, 128 + n, hb, 768);
      st16(aS2a, r, mod*128 + n, hb, 512);
    }
    __syncthreads();                               // C

    // ---- S2a: y = tanh([h0|h1]@A1 + a1)  (waves 0-7, nt=w) ----
    if (w < 8){
      f32x4 acc = {0,0,0,0};
      #pragma unroll
      for (int kc = 0; kc < 8; ++kc)
        acc = MF(frA(aS2a, l, kc, 512), frB(A1t, w, kc, 8, l), acc);
      if (hi == 0){
        int n = w*16 + li;
        #pragma unroll
        for (int jr = 0; jr < 4; ++jr)
          st16(aS2b, jr, n, f2b(tanh_f(acc[jr] + bsh[1024 + n])), 256);
      }
    }
    __syncthreads();                               // D

    // ---- S2b: logits = y@A2 + a2  (16 waves x 4 nt) ----
    {
      bf16x8 af[4];
      #pragma unroll
      for (int kc = 0; kc < 4; ++kc) af[kc] = frA(aS2b, l, kc, 256);
      #pragma unroll
      for (int q = 0; q < 4; ++q){
        int nt = w*4 + q;
        f32x4 acc = {0,0,0,0};
        #pragma unroll
        for (int kc = 0; kc < 4; ++kc)
          acc = MF(af[kc], frB(A2t, nt, kc, 4, l), acc);
        if (hi == 0){
          int n = nt*16 + li;
          #pragma unroll
          for (int jr = 0; jr < 4; ++jr)
            lgS[jr][n] = acc[jr] + bsh[1152 + n];
        }
      }
    }
    __syncthreads();                               // E

    // ---- SM: 4-way softmax * tiled h  (4 rows x 256 g) ----
    {
      int r = tid >> 8, g = tid & 255;
      float v0 = lgS[r][g],     v1 = lgS[r][256+g];
      float v2 = lgS[r][512+g], v3 = lgS[r][768+g];
      float mx = fmaxf(fmaxf(v0,v1), fmaxf(v2,v3));
      float e0 = __expf(v0-mx), e1 = __expf(v1-mx);
      float e2 = __expf(v2-mx), e3 = __expf(v3-mx);
      float inv = 1.f/(e0+e1+e2+e3);
      float h0v = hS[0][r][g & 127], h1v = hS[1][r][g & 127];
      st16(aS3a, r,   g,     f2b(e0*inv*h0v), 1024);
      st16(aS3a, r,   256+g, f2b(e1*inv*h0v), 1024);
      st16(aS3a, 8+r, g,     f2b(e2*inv*h1v), 1024);
      st16(aS3a, 8+r, 256+g, f2b(e3*inv*h1v), 1024);
    }
    __syncthreads();                               // F

    // ---- S3a: u = tanh(att@D1 + e1)  (wave: mod=w>>3, nt=w&7) ----
    {
      int mod = w >> 3, nt = w & 7;
      const u16* Dt = mod ? D11t : D10t;
      f32x4 acc = {0,0,0,0};
      #pragma unroll
      for (int kc = 0; kc < 16; ++kc)
        acc = MF(frA(aS3a, l, kc, 1024), frB(Dt, nt, kc, 16, l), acc);
      if (hi == mod*2){
        int n = nt*16 + li;
        const float* e1f = bsh + (mod ? 2432 : 2176);
        #pragma unroll
        for (int jr = 0; jr < 4; ++jr)
          st16(aS3b, mod*8 + jr, n, f2b(tanh_f(acc[jr] + e1f[n])), 256);
      }
    }
    __syncthreads();                               // G

    // ---- S3b: z = u@D2 + e2 ; write out (f32) + z feedback (bf16) ----
    {
      int mod = w >> 3, nt = w & 7;
      const u16* Dt = mod ? D21t : D20t;
      f32x4 acc = {0,0,0,0};
      #pragma unroll
      for (int kc = 0; kc < 4; ++kc)
        acc = MF(frA(aS3b, l, kc, 256), frB(Dt, nt, kc, 4, l), acc);
      if (hi == mod*2){
        int n = nt*16 + li;
        const float* e2f = bsh + (mod ? 2560 : 2304);
        #pragma unroll
        for (int jr = 0; jr < 4; ++jr){
          float z = acc[jr] + e2f[n];
          out[((size_t)t*BATCH + r0 + jr)*256 + mod*128 + n] = z;
          st16(aS1, mod*8 + jr, 256 + n, f2b(z), 768);
        }
      }
    }
    __syncthreads();                               // H
  }
}

extern "C" void kernel_launch(void* const* d_in, const int* in_sizes, int n_in,
                              void* d_out, int out_size, void* d_ws, size_t ws_size,
                              hipStream_t stream)
{
  const float* eeg = (const float*)d_in[0];
  const float* eog = (const float*)d_in[1];
  const float* Ww  = (const float*)d_in[2];
  const float* Wb  = (const float*)d_in[3];
  const float* Uw  = (const float*)d_in[4];
  const float* Ub  = (const float*)d_in[5];
  const float* Vw  = (const float*)d_in[6];
  const float* Vb  = (const float*)d_in[7];
  const float* A1  = (const float*)d_in[8];
  const float* a1  = (const float*)d_in[9];
  const float* A2  = (const float*)d_in[10];
  const float* a2  = (const float*)d_in[11];
  const float* D10 = (const float*)d_in[12];
  const float* e10 = (const float*)d_in[13];
  const float* D20 = (const float*)d_in[14];
  const float* e20 = (const float*)d_in[15];
  const float* D11 = (const float*)d_in[16];
  const float* e11 = (const float*)d_in[17];
  const float* D21 = (const float*)d_in[18];
  const float* e21 = (const float*)d_in[19];

  char* ws = (char*)d_ws;
  u16*  UVWt = (u16*)(ws);                  // 384x512 bf16 = 393216 B
  u16*  A1t  = (u16*)(ws + 393216);         // 65536 B
  u16*  A2t  = (u16*)(ws + 458752);         // 262144 B
  u16*  D10t = (u16*)(ws + 720896);         // 131072 B
  u16*  D20t = (u16*)(ws + 851968);         // 32768 B
  u16*  D11t = (u16*)(ws + 884736);         // 131072 B
  u16*  D21t = (u16*)(ws + 1015808);        // 32768 B
  float* bias = (float*)(ws + 1048576);     // 2688 f32

  auto nb = [](int n){ return dim3((unsigned)((n + 255)/256)); };
  pack_w<<<nb(65536),  256, 0, stream>>>(Ww,  UVWt, 128, 512,  0, 12);
  pack_w<<<nb(65536),  256, 0, stream>>>(Uw,  UVWt, 128, 512,  4, 12);
  pack_w<<<nb(65536),  256, 0, stream>>>(Vw,  UVWt, 128, 512,  8, 12);
  pack_w<<<nb(32768),  256, 0, stream>>>(A1,  A1t,  256, 128,  0, 8);
  pack_w<<<nb(131072), 256, 0, stream>>>(A2,  A2t,  128, 1024, 0, 4);
  pack_w<<<nb(65536),  256, 0, stream>>>(D10, D10t, 512, 128,  0, 16);
  pack_w<<<nb(16384),  256, 0, stream>>>(D20, D20t, 128, 128,  0, 4);
  pack_w<<<nb(65536),  256, 0, stream>>>(D11, D11t, 512, 128,  0, 16);
  pack_w<<<nb(16384),  256, 0, stream>>>(D21, D21t, 128, 128,  0, 4);
  pack_bias<<<nb(2688), 256, 0, stream>>>(Wb, Ub, Vb, a1, a2, e10, e20, e11, e21, bias);

  marn_mfma<<<NBLK, 1024, 0, stream>>>(eeg, eog, UVWt, A1t, A2t,
                                       D10t, D20t, D11t, D21t, bias, (float*)d_out);
}